// Round 2
// baseline (599.160 us; speedup 1.0000x reference)
//
#include <hip/hip_runtime.h>

typedef unsigned short u16;
typedef __attribute__((ext_vector_type(8))) short short8;
typedef __attribute__((ext_vector_type(8))) unsigned short u16x8;
typedef __attribute__((ext_vector_type(4))) unsigned short u16x4;
typedef __attribute__((ext_vector_type(2))) unsigned short u16x2;
typedef __attribute__((ext_vector_type(4))) float f32x4;

#define NBATCH 2
#define SEQ    4096
#define DIM    2048
#define NHEAD  16
#define HD     128
#define CH     64
#define NC     64           /* SEQ / CH */
#define MROWS  8192         /* NBATCH * SEQ */

__device__ __forceinline__ float b2f(u16 u) {
    unsigned x = ((unsigned)u) << 16;
    return __builtin_bit_cast(float, x);
}
__device__ __forceinline__ u16 f2b(float f) {
    unsigned u = __builtin_bit_cast(unsigned, f);
    u += 0x7fffu + ((u >> 16) & 1u);
    return (u16)(u >> 16);
}

__device__ __forceinline__ void gload_lds16(const u16* g, u16* l) {
    __builtin_amdgcn_global_load_lds(
        (const __attribute__((address_space(1))) void*)g,
        (__attribute__((address_space(3))) void*)l, 16, 0, 0);
}

// ---------------------------------------------------------------------------
// Unified f32->bf16 cast for x + 4 weights in ONE dispatch.
// ---------------------------------------------------------------------------
__global__ __launch_bounds__(256) void cast_all(
    const float* __restrict__ x,
    const float* __restrict__ w0, const float* __restrict__ w1,
    const float* __restrict__ w2, const float* __restrict__ w3,
    u16* __restrict__ xo,
    u16* __restrict__ o0, u16* __restrict__ o1,
    u16* __restrict__ o2, u16* __restrict__ o3)
{
    const int blk = blockIdx.x;
    const float* in;
    u16* out;
    long i;
    if (blk < 8192) {
        in = x; out = xo;
        i = (long)blk * 256 + threadIdx.x;
    } else {
        const int seg = (blk - 8192) >> 11;
        in  = seg == 0 ? w0 : seg == 1 ? w1 : seg == 2 ? w2 : w3;
        out = seg == 0 ? o0 : seg == 1 ? o1 : seg == 2 ? o2 : o3;
        i = (long)((blk - 8192) & 2047) * 256 + threadIdx.x;
    }
    f32x4 a = ((const f32x4*)in)[2 * i];
    f32x4 b = ((const f32x4*)in)[2 * i + 1];
    u16x8 o;
#pragma unroll
    for (int j = 0; j < 4; j++) { o[j] = f2b(a[j]); o[4 + j] = f2b(b[j]); }
    ((u16x8*)out)[i] = o;
}

// ---------------------------------------------------------------------------
// Deep-pipelined 256x256 GEMM core, m201-style fine phases:
//   512 thr = 8 waves (2M x 4N), BK=32, ring-4 LDS (128 KiB), depth-3
//   prefetch, counted vmcnt (8 steady; 4/0 tail), per K-tile TWO phases:
//   {4-8 ds_read_b128 || 2 global_load_lds -> [vmcnt] -> s_barrier ->
//    lgkmcnt(0)+sched_barrier(0) -> setprio(1) 16 MFMA setprio(0) -> s_barrier}
// LDS permutation (rule 21 both-sides): lane l stages global
//   (row = 2*(l>>3)+(u>>2), kslot = u&3), u = (l&7)^(l>>3); readers use
//   fl = line*64 + ((((m16&1)<<2)|quad) ^ line)*8  -> conflict-free.
// ---------------------------------------------------------------------------
#define GBM 256
#define GBN 256
#define GBK 32
#define BUFE 16384   /* u16 elems per ring slot: A 8192 + B 8192 */

struct Ctx8 {
    int wave, lane, wr, wc, m16, quad;
    int fl;          // fragment lane offset within a 512-elem (16-row) block
    long grA[2];     // per-lane global element offsets for the 2 staged blocks
    int ldso[2];     // per-lane LDS elem offsets (linear dest for gload_lds)
};

__device__ __forceinline__ Ctx8 ctx8(int K) {
    Ctx8 c;
    const int tid = threadIdx.x;
    c.wave = tid >> 6; c.lane = tid & 63;
    c.wr = c.wave >> 2; c.wc = c.wave & 3;
    c.m16 = c.lane & 15; c.quad = (c.lane >> 4) & 3;
    const int t3 = c.lane >> 3;
    const int u3 = (c.lane & 7) ^ t3;
    const int ml = 2 * t3 + (u3 >> 2);      // row within 16-row block
    const int sl = (u3 & 3) * 8;            // k element offset
#pragma unroll
    for (int i = 0; i < 2; i++) {
        const int bi = 2 * c.wave + i;      // 16-row block index (0..15)
        c.grA[i] = (long)(bi * 16 + ml) * K + sl;
        c.ldso[i] = bi * 512 + c.lane * 8;
    }
    const int line = c.m16 >> 1;
    c.fl = line * 64 + ((((c.m16 & 1) << 2) | c.quad) ^ line) * 8;
    return c;
}

// One phase: reads (af always; bf iff READB) || stage one unit || counted
// vmcnt (VMC>=0) -> barrier -> lgkm(0) -> 16 MFMA -> barrier.
template<bool READB, bool STG, int VMC>
__device__ __forceinline__ void phase8(
    const Ctx8& c, const u16* As, const u16* Bs, const int ihalf,
    short8 (&bf)[4], f32x4 (&acc)[8][4],
    const u16* pS, long off, u16* dst)
{
    short8 af[4];
#pragma unroll
    for (int t = 0; t < 4; t++)
        af[t] = *(const short8*)&As[(c.wr * 8 + ihalf * 4 + t) * 512 + c.fl];
    if (READB) {
#pragma unroll
        for (int t = 0; t < 4; t++)
            bf[t] = *(const short8*)&Bs[(c.wc * 4 + t) * 512 + c.fl];
    }
    if (STG) {
        gload_lds16(pS + c.grA[0] + off, dst + c.ldso[0]);
        gload_lds16(pS + c.grA[1] + off, dst + c.ldso[1]);
    }
    if (VMC >= 0)
        asm volatile("s_waitcnt vmcnt(%0)" :: "i"(VMC < 0 ? 0 : VMC) : "memory");
    __builtin_amdgcn_s_barrier();
    asm volatile("s_waitcnt lgkmcnt(0)" ::: "memory");
    __builtin_amdgcn_sched_barrier(0);
    __builtin_amdgcn_s_setprio(1);
#pragma unroll
    for (int i = 0; i < 4; i++)
#pragma unroll
        for (int j = 0; j < 4; j++)
            acc[ihalf * 4 + i][j] = __builtin_amdgcn_mfma_f32_16x16x32_bf16(
                af[i], bf[j], acc[ihalf * 4 + i][j], 0, 0, 0);
    __builtin_amdgcn_s_setprio(0);
    __builtin_amdgcn_s_barrier();
}

__device__ __forceinline__ void kloop8(
    const Ctx8& c, const u16* pA, const u16* pB, int K, u16* L, f32x4 (&acc)[8][4])
{
    const int NT = K >> 5;   // K-tiles of 32
    // prologue: stage tiles 0..2 into ring slots 0..2 (12 loads in flight)
#pragma unroll
    for (int t = 0; t < 3; t++) {
        u16* As = L + t * BUFE;
        u16* Bs = As + 8192;
        gload_lds16(pA + c.grA[0] + t * GBK, As + c.ldso[0]);
        gload_lds16(pA + c.grA[1] + t * GBK, As + c.ldso[1]);
        gload_lds16(pB + c.grA[0] + t * GBK, Bs + c.ldso[0]);
        gload_lds16(pB + c.grA[1] + t * GBK, Bs + c.ldso[1]);
    }
    asm volatile("s_waitcnt vmcnt(8)" ::: "memory");   // tile 0 landed
    __builtin_amdgcn_s_barrier();

    short8 bf[4];
#pragma unroll 1
    for (int u = 0; u < NT - 3; ++u) {
        const u16* As = L + (u & 3) * BUFE;
        const u16* Bs = As + 8192;
        u16* AsN = L + ((u + 3) & 3) * BUFE;
        const long off = (long)(u + 3) * GBK;
        phase8<true,  true, -1>(c, As, Bs, 0, bf, acc, pA, off, AsN);
        phase8<false, true,  8>(c, As, Bs, 1, bf, acc, pB, off, AsN + 8192);
    }
    {   // u = NT-3: no staging; wait tile NT-2 (8 outstanding -> 4)
        const u16* As = L + ((NT - 3) & 3) * BUFE;
        phase8<true,  false, -1>(c, As, As + 8192, 0, bf, acc, nullptr, 0, nullptr);
        phase8<false, false,  4>(c, As, As + 8192, 1, bf, acc, nullptr, 0, nullptr);
    }
    {   // u = NT-2: wait tile NT-1 (4 outstanding -> 0)
        const u16* As = L + ((NT - 2) & 3) * BUFE;
        phase8<true,  false, -1>(c, As, As + 8192, 0, bf, acc, nullptr, 0, nullptr);
        phase8<false, false,  0>(c, As, As + 8192, 1, bf, acc, nullptr, 0, nullptr);
    }
    {   // u = NT-1: nothing left in flight
        const u16* As = L + ((NT - 1) & 3) * BUFE;
        phase8<true,  false, -1>(c, As, As + 8192, 0, bf, acc, nullptr, 0, nullptr);
        phase8<false, false, -1>(c, As, As + 8192, 1, bf, acc, nullptr, 0, nullptr);
    }
}

// ---------------------------------------------------------------------------
// Fused QKV projection, 1-D grid (768 blocks) with XCD-chunked swizzle (T1).
//   logical by = 0..23: w = by/8 selects weight; col = (by&7)*256.
//   w=0: q normal (scaled). w=1: k normal + kt transposed. w=2: vt transposed.
// ---------------------------------------------------------------------------
__global__ __launch_bounds__(512, 2) void gemm_qkv(
    const u16* __restrict__ A,
    const u16* __restrict__ Wqb, const u16* __restrict__ Wkb, const u16* __restrict__ Wvb,
    u16* __restrict__ q, u16* __restrict__ k, u16* __restrict__ kt,
    u16* __restrict__ vt, float qscale)
{
    __shared__ __align__(16) u16 L[4 * BUFE];   // 128 KiB
    const Ctx8 c = ctx8(DIM);

    const int lid = blockIdx.x;                 // 0..767, %8==0 grid -> bijective
    const int swz = (lid & 7) * 96 + (lid >> 3);
    const int bx = swz & 31;                    // row-block
    const int by = swz >> 5;                    // 0..23
    const int w = by >> 3;
    const long row0 = (long)bx * GBM;
    const long col0 = (long)(by & 7) * GBN;
    const u16* Bw = w == 0 ? Wqb : w == 1 ? Wkb : Wvb;

    f32x4 acc[8][4];
#pragma unroll
    for (int i = 0; i < 8; i++)
#pragma unroll
        for (int j = 0; j < 4; j++) {
            f32x4 z = {0.f, 0.f, 0.f, 0.f};
            acc[i][j] = z;
        }

    kloop8(c, A + row0 * DIM, Bw + col0 * DIM, DIM, L, acc);

    const float scale = (w == 0) ? qscale : 1.0f;
#pragma unroll
    for (int i = 0; i < 8; i++) {
        const long grow0 = row0 + c.wr * 128 + i * 16 + c.quad * 4;
#pragma unroll
        for (int j = 0; j < 4; j++) {
            const long gcol = col0 + c.wc * 64 + j * 16 + c.m16;
            u16x4 p;
#pragma unroll
            for (int r = 0; r < 4; r++) p[r] = f2b(acc[i][j][r] * scale);
            if (w == 0) {
#pragma unroll
                for (int r = 0; r < 4; r++) q[(grow0 + r) * DIM + gcol] = p[r];
            } else {
                const long b = grow0 >> 12;            // batch (SEQ=4096 rows)
                const long t0 = grow0 & (SEQ - 1);
                u16* Ct = (w == 1) ? kt : vt;
                *(u16x4*)(Ct + (b * DIM + gcol) * SEQ + t0) = p;
                if (w == 1) {
#pragma unroll
                    for (int r = 0; r < 4; r++) k[(grow0 + r) * DIM + gcol] = p[r];
                }
            }
        }
    }
}

// ---------------------------------------------------------------------------
// Output GEMM: out[m][n] = sum_k o[m][k] * Wo[n][k], f32 out. 256 blocks, T1.
// ---------------------------------------------------------------------------
__global__ __launch_bounds__(512, 2) void gemm_out(
    const u16* __restrict__ A, const u16* __restrict__ Bw, float* __restrict__ C)
{
    __shared__ __align__(16) u16 L[4 * BUFE];   // 128 KiB
    const Ctx8 c = ctx8(DIM);
    const int lid = blockIdx.x;                 // 0..255
    const int swz = (lid & 7) * 32 + (lid >> 3);
    const long row0 = (long)(swz & 31) * GBM;
    const long col0 = (long)(swz >> 5) * GBN;

    f32x4 acc[8][4];
#pragma unroll
    for (int i = 0; i < 8; i++)
#pragma unroll
        for (int j = 0; j < 4; j++) {
            f32x4 z = {0.f, 0.f, 0.f, 0.f};
            acc[i][j] = z;
        }

    kloop8(c, A + row0 * DIM, Bw + col0 * DIM, DIM, L, acc);

#pragma unroll
    for (int i = 0; i < 8; i++) {
        const long grow0 = row0 + c.wr * 128 + i * 16 + c.quad * 4;
#pragma unroll
        for (int j = 0; j < 4; j++) {
            const long gcol = col0 + c.wc * 64 + j * 16 + c.m16;
#pragma unroll
            for (int r = 0; r < 4; r++)
                C[(grow0 + r) * DIM + gcol] = acc[i][j][r];
        }
    }
}

// ---------------------------------------------------------------------------
// chunk_kv (MFMA): kvT[blk][e][d] = sum_t Vt[e][t] Kt[d][t]; frags from global.
// ---------------------------------------------------------------------------
__global__ __launch_bounds__(256) void chunk_kv_mfma(
    const u16* __restrict__ Vt, const u16* __restrict__ Kt, u16* __restrict__ KV)
{
    const int tid = threadIdx.x, blk = blockIdx.x;
    const int c = blk & (NC - 1), bh = blk >> 6;
    const int wave = tid >> 6, lane = tid & 63;
    const int wr = wave >> 1, wc = wave & 1;
    const int m16 = lane & 15, quad = lane >> 4;
    const u16* vb = Vt + (long)bh * HD * SEQ + c * CH;
    const u16* kb = Kt + (long)bh * HD * SEQ + c * CH;

    f32x4 acc[4][4];
#pragma unroll
    for (int i = 0; i < 4; i++)
#pragma unroll
        for (int j = 0; j < 4; j++) {
            f32x4 z = {0.f, 0.f, 0.f, 0.f};
            acc[i][j] = z;
        }

#pragma unroll
    for (int tk = 0; tk < 2; tk++) {
        short8 af[4], bf[4];
#pragma unroll
        for (int t = 0; t < 4; t++)
            af[t] = *(const short8*)(vb + (long)(wr * 64 + t * 16 + m16) * SEQ + tk * 32 + quad * 8);
#pragma unroll
        for (int t = 0; t < 4; t++)
            bf[t] = *(const short8*)(kb + (long)(wc * 64 + t * 16 + m16) * SEQ + tk * 32 + quad * 8);
#pragma unroll
        for (int i = 0; i < 4; i++)
#pragma unroll
            for (int j = 0; j < 4; j++)
                acc[i][j] = __builtin_amdgcn_mfma_f32_16x16x32_bf16(
                    af[i], bf[j], acc[i][j], 0, 0, 0);
    }

    u16* outp = KV + (long)blk * (HD * HD);
#pragma unroll
    for (int i = 0; i < 4; i++)
#pragma unroll
        for (int j = 0; j < 4; j++)
#pragma unroll
            for (int r = 0; r < 4; r++)
                outp[(wr * 64 + i * 16 + quad * 4 + r) * HD + wc * 64 + j * 16 + m16]
                    = f2b(acc[i][j][r]);
}

// ---------------------------------------------------------------------------
// exclusive prefix over chunks, in place, u16x2 vectorized.
// ---------------------------------------------------------------------------
__global__ __launch_bounds__(256) void kv_prefix(u16* __restrict__ KV)
{
    const int bh  = blockIdx.x >> 5;
    const int sub = blockIdx.x & 31;
    const long base = (long)bh * NC * (HD * HD) + (sub * 256 + threadIdx.x) * 2;
    float s0 = 0.f, s1 = 0.f;
#pragma unroll 4
    for (int c = 0; c < NC; c++) {
        u16* p = KV + base + (long)c * (HD * HD);
        u16x2 v = *(u16x2*)p;
        u16x2 w; w[0] = f2b(s0); w[1] = f2b(s1);
        *(u16x2*)p = w;
        s0 += b2f(v[0]); s1 += b2f(v[1]);
    }
}

// ---------------------------------------------------------------------------
// chunk_out (MFMA): O = mask(Q K^T) V + Q S  per 64-token chunk.
// ---------------------------------------------------------------------------
#define AMP 72   /* padded LDS stride */

__global__ __launch_bounds__(256) void chunk_out_mfma(
    const u16* __restrict__ Q, const u16* __restrict__ Kn,
    const u16* __restrict__ Vt, const u16* __restrict__ Sb, u16* __restrict__ O)
{
    __shared__ __align__(16) u16 Am[CH * AMP];   // 9216 B

    const int tid = threadIdx.x, blk = blockIdx.x;
    const int c = blk & (NC - 1), bh = blk >> 6;
    const int h = bh & (NHEAD - 1), b = bh >> 4;
    const long rowbase = (long)b * SEQ + (long)c * CH;
    const int wave = tid >> 6, lane = tid & 63;   // wave = m-tile
    const int m16 = lane & 15, quad = lane >> 4;

    const u16* qrow = Q  + (rowbase + wave * 16 + m16) * DIM + h * HD;
    const u16* krow = Kn + rowbase * DIM + h * HD;

    short8 qa[4];
#pragma unroll
    for (int dk = 0; dk < 4; dk++)
        qa[dk] = *(const short8*)(qrow + dk * 32 + quad * 8);

    // phase 1: A = mask(Q K^T) -> LDS (A-op layout)
    f32x4 acc1[4];
#pragma unroll
    for (int jt = 0; jt < 4; jt++) {
        f32x4 z = {0.f, 0.f, 0.f, 0.f};
        acc1[jt] = z;
    }
#pragma unroll
    for (int dk = 0; dk < 4; dk++)
#pragma unroll
        for (int jt = 0; jt < 4; jt++) {
            short8 bb = *(const short8*)(krow + (long)(jt * 16 + m16) * DIM + dk * 32 + quad * 8);
            acc1[jt] = __builtin_amdgcn_mfma_f32_16x16x32_bf16(qa[dk], bb, acc1[jt], 0, 0, 0);
        }
    const int mbase = wave * 16 + quad * 4;
#pragma unroll
    for (int jt = 0; jt < 4; jt++) {
        const int j = jt * 16 + m16;
#pragma unroll
        for (int r = 0; r < 4; r++) {
            float v = (j <= mbase + r) ? acc1[jt][r] : 0.f;
            Am[(mbase + r) * AMP + j] = f2b(v);
        }
    }

    // phase 2: acc = Q * S (S^T rows d-contiguous)
    f32x4 acc[8];
#pragma unroll
    for (int et = 0; et < 8; et++) {
        f32x4 z = {0.f, 0.f, 0.f, 0.f};
        acc[et] = z;
    }
    const u16* Sg = Sb + (long)blk * (HD * HD);
#pragma unroll
    for (int dk = 0; dk < 4; dk++)
#pragma unroll
        for (int et = 0; et < 8; et++) {
            short8 sb = *(const short8*)(Sg + (et * 16 + m16) * HD + dk * 32 + quad * 8);
            acc[et] = __builtin_amdgcn_mfma_f32_16x16x32_bf16(qa[dk], sb, acc[et], 0, 0, 0);
        }

    // phase 3: acc += A * V (A from own-wave LDS rows, V^T t-contiguous)
    __syncthreads();
    const u16* vb = Vt + (long)bh * HD * SEQ + c * CH;
#pragma unroll
    for (int tk = 0; tk < 2; tk++) {
        short8 a = *(const short8*)&Am[(wave * 16 + m16) * AMP + tk * 32 + quad * 8];
#pragma unroll
        for (int et = 0; et < 8; et++) {
            short8 vbf = *(const short8*)(vb + (long)(et * 16 + m16) * SEQ + tk * 32 + quad * 8);
            acc[et] = __builtin_amdgcn_mfma_f32_16x16x32_bf16(a, vbf, acc[et], 0, 0, 0);
        }
    }

#pragma unroll
    for (int et = 0; et < 8; et++) {
        const int e = et * 16 + m16;
#pragma unroll
        for (int r = 0; r < 4; r++) {
            const int m = wave * 16 + quad * 4 + r;
            O[(rowbase + m) * DIM + h * HD + e] = f2b(acc[et][r]);
        }
    }
}

// ---------------------------------------------------------------------------
extern "C" void kernel_launch(void* const* d_in, const int* in_sizes, int n_in,
                              void* d_out, int out_size, void* d_ws, size_t ws_size,
                              hipStream_t stream)
{
    (void)in_sizes; (void)n_in; (void)out_size; (void)ws_size;
    const float* x  = (const float*)d_in[0];
    const float* Wq = (const float*)d_in[1];
    const float* Wk = (const float*)d_in[2];
    const float* Wv = (const float*)d_in[3];
    const float* Wo = (const float*)d_in[4];
    float* out = (float*)d_out;

    const long NE = (long)MROWS * DIM;        // 16,777,216 elements
    const long WE = (long)DIM * DIM;          //  4,194,304 elements
    u16* xb  = (u16*)d_ws;                    // 33.5 MB
    u16* Wqb = xb  + NE;
    u16* Wkb = Wqb + WE;
    u16* Wvb = Wkb + WE;
    u16* Wob = Wvb + WE;
    u16* q   = Wob + WE;                      // 33.5 MB each
    u16* k   = q + NE;
    u16* vt  = k + NE;                        // transposed [b,h,e][t]
    u16* kv  = vt + NE;                       // 67.1 MB (kvT per chunk)
    u16* o   = xb;                            // alias: xb dead after projections
    u16* kt  = (u16*)d_out;                   // scratch in d_out (overwritten later)

    hipLaunchKernelGGL(cast_all, dim3(16384), dim3(256), 0, stream,
                       x, Wq, Wk, Wv, Wo, xb, Wqb, Wkb, Wvb, Wob);

    const float qscale = 0.08838834764831845f;  // HD^-0.5

    hipLaunchKernelGGL(gemm_qkv, dim3(768), dim3(512), 0, stream,
                       xb, Wqb, Wkb, Wvb, q, k, kt, vt, qscale);

    hipLaunchKernelGGL(chunk_kv_mfma, dim3(NBATCH * NHEAD * NC), dim3(256), 0, stream, vt, kt, kv);
    hipLaunchKernelGGL(kv_prefix,     dim3(1024),                dim3(256), 0, stream, kv);
    hipLaunchKernelGGL(chunk_out_mfma,dim3(NBATCH * NHEAD * NC), dim3(256), 0, stream, q, k, vt, kv, o);

    hipLaunchKernelGGL(gemm_out, dim3(256), dim3(512), 0, stream, o, Wob, out);
}

// Round 3
// 587.241 us; speedup vs baseline: 1.0203x; 1.0203x over previous
//
#include <hip/hip_runtime.h>

typedef unsigned short u16;
typedef __attribute__((ext_vector_type(8))) short short8;
typedef __attribute__((ext_vector_type(8))) unsigned short u16x8;
typedef __attribute__((ext_vector_type(4))) unsigned short u16x4;
typedef __attribute__((ext_vector_type(2))) unsigned short u16x2;
typedef __attribute__((ext_vector_type(4))) float f32x4;

#define NBATCH 2
#define SEQ    4096
#define DIM    2048
#define NHEAD  16
#define HD     128
#define CH     64
#define NC     64           /* SEQ / CH */
#define MROWS  8192         /* NBATCH * SEQ */

__device__ __forceinline__ float b2f(u16 u) {
    unsigned x = ((unsigned)u) << 16;
    return __builtin_bit_cast(float, x);
}
__device__ __forceinline__ u16 f2b(float f) {
    unsigned u = __builtin_bit_cast(unsigned, f);
    u += 0x7fffu + ((u >> 16) & 1u);
    return (u16)(u >> 16);
}

__device__ __forceinline__ void gload_lds16(const u16* g, u16* l) {
    __builtin_amdgcn_global_load_lds(
        (const __attribute__((address_space(1))) void*)g,
        (__attribute__((address_space(3))) void*)l, 16, 0, 0);
}

// ---------------------------------------------------------------------------
// Unified f32->bf16 cast for x + 4 weights in ONE dispatch.
// ---------------------------------------------------------------------------
__global__ __launch_bounds__(256) void cast_all(
    const float* __restrict__ x,
    const float* __restrict__ w0, const float* __restrict__ w1,
    const float* __restrict__ w2, const float* __restrict__ w3,
    u16* __restrict__ xo,
    u16* __restrict__ o0, u16* __restrict__ o1,
    u16* __restrict__ o2, u16* __restrict__ o3)
{
    const int blk = blockIdx.x;
    const float* in;
    u16* out;
    long i;
    if (blk < 8192) {
        in = x; out = xo;
        i = (long)blk * 256 + threadIdx.x;
    } else {
        const int seg = (blk - 8192) >> 11;
        in  = seg == 0 ? w0 : seg == 1 ? w1 : seg == 2 ? w2 : w3;
        out = seg == 0 ? o0 : seg == 1 ? o1 : seg == 2 ? o2 : o3;
        i = (long)((blk - 8192) & 2047) * 256 + threadIdx.x;
    }
    f32x4 a = ((const f32x4*)in)[2 * i];
    f32x4 b = ((const f32x4*)in)[2 * i + 1];
    u16x8 o;
#pragma unroll
    for (int j = 0; j < 4; j++) { o[j] = f2b(a[j]); o[4 + j] = f2b(b[j]); }
    ((u16x8*)out)[i] = o;
}

// ---------------------------------------------------------------------------
// Deep-pipelined 256x256 GEMM core, fine phases, compiler-scheduled lgkm:
//   512 thr = 8 waves (2M x 4N), BK=32, ring-4 LDS (128 KiB), depth-3
//   prefetch, counted vmcnt (8 steady; 4/0 tail). Per K-tile TWO phases:
//   {ds_read frags || 2 global_load_lds -> [vmcnt] -> s_barrier ->
//    setprio(1) 16 MFMA setprio(0) -> s_barrier}.
//   No manual lgkmcnt(0)/sched_barrier: plain-load ds_reads let the compiler
//   emit fine-grained lgkmcnt(N) so MFMAs overlap trailing reads (m97 style).
// LDS permutation (rule 21 both-sides): lane l stages global
//   (row = 2*(l>>3)+(u>>2), kslot = u&3), u = (l&7)^(l>>3); readers use
//   fl = line*64 + ((((m16&1)<<2)|quad) ^ line)*8  -> conflict-free.
// ---------------------------------------------------------------------------
#define GBM 256
#define GBN 256
#define GBK 32
#define BUFE 16384   /* u16 elems per ring slot: A 8192 + B 8192 */

struct Ctx8 {
    int wave, lane, wr, wc, m16, quad;
    int fl;          // fragment lane offset within a 512-elem (16-row) block
    long grA[2];     // per-lane global element offsets for the 2 staged blocks
    int ldso[2];     // per-lane LDS elem offsets (linear dest for gload_lds)
};

__device__ __forceinline__ Ctx8 ctx8(int K) {
    Ctx8 c;
    const int tid = threadIdx.x;
    c.wave = tid >> 6; c.lane = tid & 63;
    c.wr = c.wave >> 2; c.wc = c.wave & 3;
    c.m16 = c.lane & 15; c.quad = (c.lane >> 4) & 3;
    const int t3 = c.lane >> 3;
    const int u3 = (c.lane & 7) ^ t3;
    const int ml = 2 * t3 + (u3 >> 2);      // row within 16-row block
    const int sl = (u3 & 3) * 8;            // k element offset
#pragma unroll
    for (int i = 0; i < 2; i++) {
        const int bi = 2 * c.wave + i;      // 16-row block index (0..15)
        c.grA[i] = (long)(bi * 16 + ml) * K + sl;
        c.ldso[i] = bi * 512 + c.lane * 8;
    }
    const int line = c.m16 >> 1;
    c.fl = line * 64 + ((((c.m16 & 1) << 2) | c.quad) ^ line) * 8;
    return c;
}

// One phase: reads (af always; bf iff READB) || stage one unit || counted
// vmcnt (VMC>=0) -> barrier -> 16 MFMA -> barrier.
template<bool READB, bool STG, int VMC>
__device__ __forceinline__ void phase8(
    const Ctx8& c, const u16* As, const u16* Bs, const int ihalf,
    short8 (&bf)[4], f32x4 (&acc)[8][4],
    const u16* pS, long off, u16* dst)
{
    short8 af[4];
#pragma unroll
    for (int t = 0; t < 4; t++)
        af[t] = *(const short8*)&As[(c.wr * 8 + ihalf * 4 + t) * 512 + c.fl];
    if (READB) {
#pragma unroll
        for (int t = 0; t < 4; t++)
            bf[t] = *(const short8*)&Bs[(c.wc * 4 + t) * 512 + c.fl];
    }
    if (STG) {
        gload_lds16(pS + c.grA[0] + off, dst + c.ldso[0]);
        gload_lds16(pS + c.grA[1] + off, dst + c.ldso[1]);
    }
    if (VMC >= 0)
        asm volatile("s_waitcnt vmcnt(%0)" :: "i"(VMC < 0 ? 0 : VMC) : "memory");
    __builtin_amdgcn_s_barrier();
    __builtin_amdgcn_s_setprio(1);
#pragma unroll
    for (int i = 0; i < 4; i++)
#pragma unroll
        for (int j = 0; j < 4; j++)
            acc[ihalf * 4 + i][j] = __builtin_amdgcn_mfma_f32_16x16x32_bf16(
                af[i], bf[j], acc[ihalf * 4 + i][j], 0, 0, 0);
    __builtin_amdgcn_s_setprio(0);
    __builtin_amdgcn_s_barrier();
}

__device__ __forceinline__ void kloop8(
    const Ctx8& c, const u16* pA, const u16* pB, int K, u16* L, f32x4 (&acc)[8][4])
{
    const int NT = K >> 5;   // K-tiles of 32
    // prologue: stage tiles 0..2 into ring slots 0..2 (12 loads in flight)
#pragma unroll
    for (int t = 0; t < 3; t++) {
        u16* As = L + t * BUFE;
        u16* Bs = As + 8192;
        gload_lds16(pA + c.grA[0] + t * GBK, As + c.ldso[0]);
        gload_lds16(pA + c.grA[1] + t * GBK, As + c.ldso[1]);
        gload_lds16(pB + c.grA[0] + t * GBK, Bs + c.ldso[0]);
        gload_lds16(pB + c.grA[1] + t * GBK, Bs + c.ldso[1]);
    }
    asm volatile("s_waitcnt vmcnt(8)" ::: "memory");   // tile 0 landed
    __builtin_amdgcn_s_barrier();

    short8 bf[4];
#pragma unroll 1
    for (int u = 0; u < NT - 3; ++u) {
        const u16* As = L + (u & 3) * BUFE;
        const u16* Bs = As + 8192;
        u16* AsN = L + ((u + 3) & 3) * BUFE;
        const long off = (long)(u + 3) * GBK;
        phase8<true,  true, -1>(c, As, Bs, 0, bf, acc, pA, off, AsN);
        phase8<false, true,  8>(c, As, Bs, 1, bf, acc, pB, off, AsN + 8192);
    }
    {   // u = NT-3: no staging; wait tile NT-2 (8 outstanding -> 4)
        const u16* As = L + ((NT - 3) & 3) * BUFE;
        phase8<true,  false, -1>(c, As, As + 8192, 0, bf, acc, nullptr, 0, nullptr);
        phase8<false, false,  4>(c, As, As + 8192, 1, bf, acc, nullptr, 0, nullptr);
    }
    {   // u = NT-2: wait tile NT-1 (4 outstanding -> 0)
        const u16* As = L + ((NT - 2) & 3) * BUFE;
        phase8<true,  false, -1>(c, As, As + 8192, 0, bf, acc, nullptr, 0, nullptr);
        phase8<false, false,  0>(c, As, As + 8192, 1, bf, acc, nullptr, 0, nullptr);
    }
    {   // u = NT-1: nothing left in flight
        const u16* As = L + ((NT - 1) & 3) * BUFE;
        phase8<true,  false, -1>(c, As, As + 8192, 0, bf, acc, nullptr, 0, nullptr);
        phase8<false, false, -1>(c, As, As + 8192, 1, bf, acc, nullptr, 0, nullptr);
    }
}

// ---------------------------------------------------------------------------
// Fused QKV projection: grid (MROWS/256, 24) 2D (round-1 mapping, measured
// best FETCH). w = y/8 selects weight.
//   w=0: q normal (scaled). w=1: k normal + kt transposed. w=2: vt transposed.
// ---------------------------------------------------------------------------
__global__ __launch_bounds__(512, 2) void gemm_qkv(
    const u16* __restrict__ A,
    const u16* __restrict__ Wqb, const u16* __restrict__ Wkb, const u16* __restrict__ Wvb,
    u16* __restrict__ q, u16* __restrict__ k, u16* __restrict__ kt,
    u16* __restrict__ vt, float qscale)
{
    __shared__ __align__(16) u16 L[4 * BUFE];   // 128 KiB
    const Ctx8 c = ctx8(DIM);

    const int w = blockIdx.y >> 3;
    const long row0 = (long)blockIdx.x * GBM;
    const long col0 = (long)(blockIdx.y & 7) * GBN;
    const u16* Bw = w == 0 ? Wqb : w == 1 ? Wkb : Wvb;

    f32x4 acc[8][4];
#pragma unroll
    for (int i = 0; i < 8; i++)
#pragma unroll
        for (int j = 0; j < 4; j++) {
            f32x4 z = {0.f, 0.f, 0.f, 0.f};
            acc[i][j] = z;
        }

    kloop8(c, A + row0 * DIM, Bw + col0 * DIM, DIM, L, acc);

    const float scale = (w == 0) ? qscale : 1.0f;
#pragma unroll
    for (int i = 0; i < 8; i++) {
        const long grow0 = row0 + c.wr * 128 + i * 16 + c.quad * 4;
#pragma unroll
        for (int j = 0; j < 4; j++) {
            const long gcol = col0 + c.wc * 64 + j * 16 + c.m16;
            u16x4 p;
#pragma unroll
            for (int r = 0; r < 4; r++) p[r] = f2b(acc[i][j][r] * scale);
            if (w == 0) {
#pragma unroll
                for (int r = 0; r < 4; r++) q[(grow0 + r) * DIM + gcol] = p[r];
            } else {
                const long b = grow0 >> 12;            // batch (SEQ=4096 rows)
                const long t0 = grow0 & (SEQ - 1);
                u16* Ct = (w == 1) ? kt : vt;
                *(u16x4*)(Ct + (b * DIM + gcol) * SEQ + t0) = p;
                if (w == 1) {
#pragma unroll
                    for (int r = 0; r < 4; r++) k[(grow0 + r) * DIM + gcol] = p[r];
                }
            }
        }
    }
}

// ---------------------------------------------------------------------------
// Output GEMM: out[m][n] = sum_k o[m][k] * Wo[n][k], f32 out. 2D grid (32,8).
// ---------------------------------------------------------------------------
__global__ __launch_bounds__(512, 2) void gemm_out(
    const u16* __restrict__ A, const u16* __restrict__ Bw, float* __restrict__ C)
{
    __shared__ __align__(16) u16 L[4 * BUFE];   // 128 KiB
    const Ctx8 c = ctx8(DIM);
    const long row0 = (long)blockIdx.x * GBM;
    const long col0 = (long)blockIdx.y * GBN;

    f32x4 acc[8][4];
#pragma unroll
    for (int i = 0; i < 8; i++)
#pragma unroll
        for (int j = 0; j < 4; j++) {
            f32x4 z = {0.f, 0.f, 0.f, 0.f};
            acc[i][j] = z;
        }

    kloop8(c, A + row0 * DIM, Bw + col0 * DIM, DIM, L, acc);

#pragma unroll
    for (int i = 0; i < 8; i++) {
        const long grow0 = row0 + c.wr * 128 + i * 16 + c.quad * 4;
#pragma unroll
        for (int j = 0; j < 4; j++) {
            const long gcol = col0 + c.wc * 64 + j * 16 + c.m16;
#pragma unroll
            for (int r = 0; r < 4; r++)
                C[(grow0 + r) * DIM + gcol] = acc[i][j][r];
        }
    }
}

// ---------------------------------------------------------------------------
// Fused chunk_kv + exclusive prefix: state S[e][d] lives in ACC registers
// across the serial 64-chunk loop; each chunk writes the EXCLUSIVE prefix
// (state before update) as bf16, then S += K_c^T V_c via MFMA.
// Grid: 32 bh * 4 sub-tiles (64x64 of the 128x128 state) = 128 blocks,
// 256 thr = 4 waves (2x2 of 32x32). Manual 2-stage load pipeline.
// Eliminates the old 67 MB KV write + 67 MB prefix re-read round trip.
// ---------------------------------------------------------------------------
__global__ __launch_bounds__(256) void chunk_kv_prefix(
    const u16* __restrict__ Vt, const u16* __restrict__ Kt, u16* __restrict__ KV)
{
    const int tid = threadIdx.x;
    const int bh = blockIdx.x >> 2, tile = blockIdx.x & 3;
    const int e0 = (tile >> 1) * 64, d0 = (tile & 1) * 64;
    const int wave = tid >> 6, lane = tid & 63;
    const int wr = wave >> 1, wc = wave & 1;          // 2x2 waves of 32x32
    const int m16 = lane & 15, quad = lane >> 4;

    const u16* vb = Vt + ((long)bh * HD + e0 + wr * 32) * SEQ;   // A rows (e)
    const u16* kb = Kt + ((long)bh * HD + d0 + wc * 32) * SEQ;   // B rows (d)
    u16* outb = KV + (long)bh * NC * (HD * HD);

    f32x4 acc[2][2];
#pragma unroll
    for (int i = 0; i < 2; i++)
#pragma unroll
        for (int j = 0; j < 2; j++) {
            f32x4 z = {0.f, 0.f, 0.f, 0.f};
            acc[i][j] = z;
        }

#define KVP_LOAD(AF, BF, cc)                                                   \
    {                                                                          \
        const long t0 = (long)(cc) * CH + quad * 8;                            \
        _Pragma("unroll")                                                      \
        for (int i = 0; i < 2; i++) {                                          \
            AF[i][0] = *(const short8*)(vb + (long)(i * 16 + m16) * SEQ + t0);      \
            AF[i][1] = *(const short8*)(vb + (long)(i * 16 + m16) * SEQ + t0 + 32); \
            BF[i][0] = *(const short8*)(kb + (long)(i * 16 + m16) * SEQ + t0);      \
            BF[i][1] = *(const short8*)(kb + (long)(i * 16 + m16) * SEQ + t0 + 32); \
        }                                                                      \
    }

#define KVP_STEP(AF, BF, cc)                                                   \
    {                                                                          \
        u16* op = outb + (long)(cc) * (HD * HD);                               \
        _Pragma("unroll")                                                      \
        for (int i = 0; i < 2; i++)                                            \
            _Pragma("unroll")                                                  \
            for (int j = 0; j < 2; j++)                                        \
                _Pragma("unroll")                                              \
                for (int r = 0; r < 4; r++)                                    \
                    op[(long)(e0 + wr * 32 + i * 16 + quad * 4 + r) * HD       \
                       + d0 + wc * 32 + j * 16 + m16] = f2b(acc[i][j][r]);     \
        _Pragma("unroll")                                                      \
        for (int tk = 0; tk < 2; tk++)                                         \
            _Pragma("unroll")                                                  \
            for (int i = 0; i < 2; i++)                                        \
                _Pragma("unroll")                                              \
                for (int j = 0; j < 2; j++)                                    \
                    acc[i][j] = __builtin_amdgcn_mfma_f32_16x16x32_bf16(       \
                        AF[i][tk], BF[j][tk], acc[i][j], 0, 0, 0);             \
    }

    short8 a0[2][2], b0[2][2], a1[2][2], b1[2][2];
    KVP_LOAD(a0, b0, 0);
#pragma unroll 1
    for (int cc = 0; cc < NC; cc += 2) {
        KVP_LOAD(a1, b1, cc + 1);          // prefetch odd chunk
        KVP_STEP(a0, b0, cc);              // write exclusive state, update
        if (cc + 2 < NC) KVP_LOAD(a0, b0, cc + 2);  // prefetch next even
        KVP_STEP(a1, b1, cc + 1);
    }
#undef KVP_LOAD
#undef KVP_STEP
}

// ---------------------------------------------------------------------------
// chunk_out (MFMA): O = mask(Q K^T) V + Q S  per 64-token chunk.
// ---------------------------------------------------------------------------
#define AMP 72   /* padded LDS stride */

__global__ __launch_bounds__(256) void chunk_out_mfma(
    const u16* __restrict__ Q, const u16* __restrict__ Kn,
    const u16* __restrict__ Vt, const u16* __restrict__ Sb, u16* __restrict__ O)
{
    __shared__ __align__(16) u16 Am[CH * AMP];   // 9216 B

    const int tid = threadIdx.x, blk = blockIdx.x;
    const int c = blk & (NC - 1), bh = blk >> 6;
    const int h = bh & (NHEAD - 1), b = bh >> 4;
    const long rowbase = (long)b * SEQ + (long)c * CH;
    const int wave = tid >> 6, lane = tid & 63;   // wave = m-tile
    const int m16 = lane & 15, quad = lane >> 4;

    const u16* qrow = Q  + (rowbase + wave * 16 + m16) * DIM + h * HD;
    const u16* krow = Kn + rowbase * DIM + h * HD;

    short8 qa[4];
#pragma unroll
    for (int dk = 0; dk < 4; dk++)
        qa[dk] = *(const short8*)(qrow + dk * 32 + quad * 8);

    // phase 1: A = mask(Q K^T) -> LDS (A-op layout)
    f32x4 acc1[4];
#pragma unroll
    for (int jt = 0; jt < 4; jt++) {
        f32x4 z = {0.f, 0.f, 0.f, 0.f};
        acc1[jt] = z;
    }
#pragma unroll
    for (int dk = 0; dk < 4; dk++)
#pragma unroll
        for (int jt = 0; jt < 4; jt++) {
            short8 bb = *(const short8*)(krow + (long)(jt * 16 + m16) * DIM + dk * 32 + quad * 8);
            acc1[jt] = __builtin_amdgcn_mfma_f32_16x16x32_bf16(qa[dk], bb, acc1[jt], 0, 0, 0);
        }
    const int mbase = wave * 16 + quad * 4;
#pragma unroll
    for (int jt = 0; jt < 4; jt++) {
        const int j = jt * 16 + m16;
#pragma unroll
        for (int r = 0; r < 4; r++) {
            float v = (j <= mbase + r) ? acc1[jt][r] : 0.f;
            Am[(mbase + r) * AMP + j] = f2b(v);
        }
    }

    // phase 2: acc = Q * S (S^T rows d-contiguous)
    f32x4 acc[8];
#pragma unroll
    for (int et = 0; et < 8; et++) {
        f32x4 z = {0.f, 0.f, 0.f, 0.f};
        acc[et] = z;
    }
    const u16* Sg = Sb + (long)blk * (HD * HD);
#pragma unroll
    for (int dk = 0; dk < 4; dk++)
#pragma unroll
        for (int et = 0; et < 8; et++) {
            short8 sb = *(const short8*)(Sg + (et * 16 + m16) * HD + dk * 32 + quad * 8);
            acc[et] = __builtin_amdgcn_mfma_f32_16x16x32_bf16(qa[dk], sb, acc[et], 0, 0, 0);
        }

    // phase 3: acc += A * V (A from own-wave LDS rows, V^T t-contiguous)
    __syncthreads();
    const u16* vb = Vt + (long)bh * HD * SEQ + c * CH;
#pragma unroll
    for (int tk = 0; tk < 2; tk++) {
        short8 a = *(const short8*)&Am[(wave * 16 + m16) * AMP + tk * 32 + quad * 8];
#pragma unroll
        for (int et = 0; et < 8; et++) {
            short8 vbf = *(const short8*)(vb + (long)(et * 16 + m16) * SEQ + tk * 32 + quad * 8);
            acc[et] = __builtin_amdgcn_mfma_f32_16x16x32_bf16(a, vbf, acc[et], 0, 0, 0);
        }
    }

#pragma unroll
    for (int et = 0; et < 8; et++) {
        const int e = et * 16 + m16;
#pragma unroll
        for (int r = 0; r < 4; r++) {
            const int m = wave * 16 + quad * 4 + r;
            O[(rowbase + m) * DIM + h * HD + e] = f2b(acc[et][r]);
        }
    }
}

// ---------------------------------------------------------------------------
extern "C" void kernel_launch(void* const* d_in, const int* in_sizes, int n_in,
                              void* d_out, int out_size, void* d_ws, size_t ws_size,
                              hipStream_t stream)
{
    (void)in_sizes; (void)n_in; (void)out_size; (void)ws_size;
    const float* x  = (const float*)d_in[0];
    const float* Wq = (const float*)d_in[1];
    const float* Wk = (const float*)d_in[2];
    const float* Wv = (const float*)d_in[3];
    const float* Wo = (const float*)d_in[4];
    float* out = (float*)d_out;

    const long NE = (long)MROWS * DIM;        // 16,777,216 elements
    const long WE = (long)DIM * DIM;          //  4,194,304 elements
    u16* xb  = (u16*)d_ws;                    // 33.5 MB
    u16* Wqb = xb  + NE;
    u16* Wkb = Wqb + WE;
    u16* Wvb = Wkb + WE;
    u16* Wob = Wvb + WE;
    u16* q   = Wob + WE;                      // 33.5 MB each
    u16* k   = q + NE;
    u16* vt  = k + NE;                        // transposed [b,h,e][t]
    u16* kv  = vt + NE;                       // 67.1 MB (prefix state per chunk)
    u16* o   = xb;                            // alias: xb dead after projections
    u16* kt  = (u16*)d_out;                   // scratch in d_out (overwritten later)

    hipLaunchKernelGGL(cast_all, dim3(16384), dim3(256), 0, stream,
                       x, Wq, Wk, Wv, Wo, xb, Wqb, Wkb, Wvb, Wob);

    const float qscale = 0.08838834764831845f;  // HD^-0.5

    hipLaunchKernelGGL(gemm_qkv, dim3(MROWS / GBM, 24), dim3(512), 0, stream,
                       xb, Wqb, Wkb, Wvb, q, k, kt, vt, qscale);

    hipLaunchKernelGGL(chunk_kv_prefix, dim3(128), dim3(256), 0, stream, vt, kt, kv);
    hipLaunchKernelGGL(chunk_out_mfma,  dim3(NBATCH * NHEAD * NC), dim3(256), 0, stream, q, k, vt, kv, o);

    hipLaunchKernelGGL(gemm_out, dim3(MROWS / GBM, DIM / GBN), dim3(512), 0, stream, o, Wob, out);
}

// Round 5
// 532.621 us; speedup vs baseline: 1.1249x; 1.1026x over previous
//
#include <hip/hip_runtime.h>

typedef unsigned short u16;
typedef __attribute__((ext_vector_type(8))) short short8;
typedef __attribute__((ext_vector_type(8))) unsigned short u16x8;
typedef __attribute__((ext_vector_type(4))) unsigned short u16x4;
typedef __attribute__((ext_vector_type(2))) unsigned short u16x2;
typedef __attribute__((ext_vector_type(4))) float f32x4;

#define NBATCH 2
#define SEQ    4096
#define DIM    2048
#define NHEAD  16
#define HD     128
#define CH     64
#define NC     64           /* SEQ / CH */
#define MROWS  8192         /* NBATCH * SEQ */

__device__ __forceinline__ float b2f(u16 u) {
    unsigned x = ((unsigned)u) << 16;
    return __builtin_bit_cast(float, x);
}
__device__ __forceinline__ u16 f2b(float f) {
    unsigned u = __builtin_bit_cast(unsigned, f);
    u += 0x7fffu + ((u >> 16) & 1u);
    return (u16)(u >> 16);
}

__device__ __forceinline__ void gload_lds16(const u16* g, u16* l) {
    __builtin_amdgcn_global_load_lds(
        (const __attribute__((address_space(1))) void*)g,
        (__attribute__((address_space(3))) void*)l, 16, 0, 0);
}

// ---------------------------------------------------------------------------
// Unified f32->bf16 cast for x + 4 weights in ONE dispatch.
// ---------------------------------------------------------------------------
__global__ __launch_bounds__(256) void cast_all(
    const float* __restrict__ x,
    const float* __restrict__ w0, const float* __restrict__ w1,
    const float* __restrict__ w2, const float* __restrict__ w3,
    u16* __restrict__ xo,
    u16* __restrict__ o0, u16* __restrict__ o1,
    u16* __restrict__ o2, u16* __restrict__ o3)
{
    const int blk = blockIdx.x;
    const float* in;
    u16* out;
    long i;
    if (blk < 8192) {
        in = x; out = xo;
        i = (long)blk * 256 + threadIdx.x;
    } else {
        const int seg = (blk - 8192) >> 11;
        in  = seg == 0 ? w0 : seg == 1 ? w1 : seg == 2 ? w2 : w3;
        out = seg == 0 ? o0 : seg == 1 ? o1 : seg == 2 ? o2 : o3;
        i = (long)((blk - 8192) & 2047) * 256 + threadIdx.x;
    }
    f32x4 a = ((const f32x4*)in)[2 * i];
    f32x4 b = ((const f32x4*)in)[2 * i + 1];
    u16x8 o;
#pragma unroll
    for (int j = 0; j < 4; j++) { o[j] = f2b(a[j]); o[4 + j] = f2b(b[j]); }
    ((u16x8*)out)[i] = o;
}

// ---------------------------------------------------------------------------
// Deep-pipelined 256x256 GEMM core with REGISTER-DOUBLE-BUFFERED fragments:
//   512 thr = 8 waves (2M x 4N), BK=32, ring-4 LDS (128 KiB), depth-3
//   prefetch, counted vmcnt (6 steady; 4/0 tail), ONE barrier per phase.
//   Each phase: barrier -> [pre-read NEXT phase's frags from LDS ||
//   stage half-tile u+3] -> 16 MFMA on frags read LAST phase. LDS reads
//   overlap MFMA (separate pipes, independent regs) -> per-tile cost
//   max(LDS,MFMA) instead of sum.
// LDS permutation (rule 21 both-sides): lane l stages global
//   (row = 2*(l>>3)+(u>>2), kslot = u&3), u = (l&7)^(l>>3); readers use
//   fl = line*64 + ((((m16&1)<<2)|quad) ^ line)*8  -> conflict-free.
// ---------------------------------------------------------------------------
#define GBM 256
#define GBN 256
#define GBK 32
#define BUFE 16384   /* u16 elems per ring slot: A 8192 + B 8192 */

struct Ctx8 {
    int wave, lane, wr, wc, m16, quad;
    int fl;          // fragment lane offset within a 512-elem (16-row) block
    long grA[2];     // per-lane global element offsets for the 2 staged blocks
    int ldso[2];     // per-lane LDS elem offsets (linear dest for gload_lds)
};

__device__ __forceinline__ Ctx8 ctx8(int K) {
    Ctx8 c;
    const int tid = threadIdx.x;
    c.wave = tid >> 6; c.lane = tid & 63;
    c.wr = c.wave >> 2; c.wc = c.wave & 3;
    c.m16 = c.lane & 15; c.quad = (c.lane >> 4) & 3;
    const int t3 = c.lane >> 3;
    const int u3 = (c.lane & 7) ^ t3;
    const int ml = 2 * t3 + (u3 >> 2);      // row within 16-row block
    const int sl = (u3 & 3) * 8;            // k element offset
#pragma unroll
    for (int i = 0; i < 2; i++) {
        const int bi = 2 * c.wave + i;      // 16-row block index (0..15)
        c.grA[i] = (long)(bi * 16 + ml) * K + sl;
        c.ldso[i] = bi * 512 + c.lane * 8;
    }
    const int line = c.m16 >> 1;
    c.fl = line * 64 + ((((c.m16 & 1) << 2) | c.quad) ^ line) * 8;
    return c;
}

// One K-32 tile, 2 phases. afC: consumed in phase0 (loaded last tile's p1).
// afN: loaded p0, consumed p1. bfC: consumed both phases. bfN: loaded p1
// for the NEXT tile (caller alternates bfC/bfN).
template<bool STG, int VMC, bool PRE1>
__device__ __forceinline__ void gstep(
    const Ctx8& c, u16* L, int u,
    short8 (&afC)[4], short8 (&afN)[4],
    short8 (&bfC)[4], short8 (&bfN)[4],
    f32x4 (&acc)[8][4],
    const u16* pA, const u16* pB)
{
    const u16* S0 = L + (u & 3) * BUFE;
    const u16* S1 = L + ((u + 1) & 3) * BUFE;
    u16* SN = L + ((u + 3) & 3) * BUFE;
    const long off = (long)(u + 3) * GBK;

    // ---- phase 0: MFMA rows 0..63 of this wave's tile ----
    __builtin_amdgcn_s_barrier();
#pragma unroll
    for (int t = 0; t < 4; t++)
        afN[t] = *(const short8*)&S0[(c.wr * 8 + 4 + t) * 512 + c.fl];
    if (STG) {
        gload_lds16(pA + c.grA[0] + off, SN + c.ldso[0]);
        gload_lds16(pA + c.grA[1] + off, SN + c.ldso[1]);
    }
    __builtin_amdgcn_s_setprio(1);
#pragma unroll
    for (int i = 0; i < 4; i++)
#pragma unroll
        for (int j = 0; j < 4; j++)
            acc[i][j] = __builtin_amdgcn_mfma_f32_16x16x32_bf16(
                afC[i], bfC[j], acc[i][j], 0, 0, 0);
    __builtin_amdgcn_s_setprio(0);

    // ---- phase 1: MFMA rows 64..127 ----
    if (VMC >= 0)
        asm volatile("s_waitcnt vmcnt(%0)" :: "i"(VMC < 0 ? 0 : VMC) : "memory");
    __builtin_amdgcn_s_barrier();
    if (PRE1) {
#pragma unroll
        for (int t = 0; t < 4; t++)
            afC[t] = *(const short8*)&S1[(c.wr * 8 + t) * 512 + c.fl];
#pragma unroll
        for (int t = 0; t < 4; t++)
            bfN[t] = *(const short8*)&S1[8192 + (c.wc * 4 + t) * 512 + c.fl];
    }
    if (STG) {
        gload_lds16(pB + c.grA[0] + off, SN + 8192 + c.ldso[0]);
        gload_lds16(pB + c.grA[1] + off, SN + 8192 + c.ldso[1]);
    }
    __builtin_amdgcn_s_setprio(1);
#pragma unroll
    for (int i = 0; i < 4; i++)
#pragma unroll
        for (int j = 0; j < 4; j++)
            acc[4 + i][j] = __builtin_amdgcn_mfma_f32_16x16x32_bf16(
                afN[i], bfC[j], acc[4 + i][j], 0, 0, 0);
    __builtin_amdgcn_s_setprio(0);
}

__device__ __forceinline__ void kloop8(
    const Ctx8& c, const u16* pA, const u16* pB, int K, u16* L, f32x4 (&acc)[8][4])
{
    const int NT = K >> 5;   // 64 K-tiles of 32
    // prologue: stage tiles 0..2 into ring slots 0..2 (12 loads in flight)
#pragma unroll
    for (int t = 0; t < 3; t++) {
        u16* As = L + t * BUFE;
        gload_lds16(pA + c.grA[0] + t * GBK, As + c.ldso[0]);
        gload_lds16(pA + c.grA[1] + t * GBK, As + c.ldso[1]);
        gload_lds16(pB + c.grA[0] + t * GBK, As + 8192 + c.ldso[0]);
        gload_lds16(pB + c.grA[1] + t * GBK, As + 8192 + c.ldso[1]);
    }
    short8 afA[4], afB[4], bfA[4], bfB[4];
    asm volatile("s_waitcnt vmcnt(8)" ::: "memory");   // tile 0 landed
    __builtin_amdgcn_s_barrier();
#pragma unroll
    for (int t = 0; t < 4; t++)
        afA[t] = *(const short8*)&L[(c.wr * 8 + t) * 512 + c.fl];
#pragma unroll
    for (int t = 0; t < 4; t++)
        bfA[t] = *(const short8*)&L[8192 + (c.wc * 4 + t) * 512 + c.fl];

#pragma unroll 1
    for (int u = 0; u < NT - 4; u += 2) {   // tiles 0..59, stage up to 62
        gstep<true, 6, true>(c, L, u,     afA, afB, bfA, bfB, acc, pA, pB);
        gstep<true, 6, true>(c, L, u + 1, afA, afB, bfB, bfA, acc, pA, pB);
    }
    // tile 60: last staging (tile 63); vmcnt(6) -> tile 61 ready
    gstep<true,  6, true >(c, L, NT - 4, afA, afB, bfA, bfB, acc, pA, pB);
    // tile 61: vmcnt(4) -> tile 62 ready (A63,B63 stay in flight)
    gstep<false, 4, true >(c, L, NT - 3, afA, afB, bfB, bfA, acc, pA, pB);
    // tile 62: vmcnt(0) -> tile 63 ready
    gstep<false, 0, true >(c, L, NT - 2, afA, afB, bfA, bfB, acc, pA, pB);
    // tile 63: nothing left to wait for or pre-read
    gstep<false, -1, false>(c, L, NT - 1, afA, afB, bfB, bfA, acc, pA, pB);
}

// ---------------------------------------------------------------------------
// Fused QKV projection: grid (MROWS/256, 24). w = y/8 selects weight.
//   w=0: q normal (scaled). w=1: k normal + kt transposed. w=2: vt transposed.
// ---------------------------------------------------------------------------
__global__ __launch_bounds__(512, 2) void gemm_qkv(
    const u16* __restrict__ A,
    const u16* __restrict__ Wqb, const u16* __restrict__ Wkb, const u16* __restrict__ Wvb,
    u16* __restrict__ q, u16* __restrict__ k, u16* __restrict__ kt,
    u16* __restrict__ vt, float qscale)
{
    __shared__ __align__(16) u16 L[4 * BUFE];   // 128 KiB
    const Ctx8 c = ctx8(DIM);

    const int w = blockIdx.y >> 3;
    const long row0 = (long)blockIdx.x * GBM;
    const long col0 = (long)(blockIdx.y & 7) * GBN;
    const u16* Bw = w == 0 ? Wqb : w == 1 ? Wkb : Wvb;

    f32x4 acc[8][4];
#pragma unroll
    for (int i = 0; i < 8; i++)
#pragma unroll
        for (int j = 0; j < 4; j++) {
            f32x4 z = {0.f, 0.f, 0.f, 0.f};
            acc[i][j] = z;
        }

    kloop8(c, A + row0 * DIM, Bw + col0 * DIM, DIM, L, acc);

    const float scale = (w == 0) ? qscale : 1.0f;
#pragma unroll
    for (int i = 0; i < 8; i++) {
        const long grow0 = row0 + c.wr * 128 + i * 16 + c.quad * 4;
#pragma unroll
        for (int j = 0; j < 4; j++) {
            const long gcol = col0 + c.wc * 64 + j * 16 + c.m16;
            u16x4 p;
#pragma unroll
            for (int r = 0; r < 4; r++) p[r] = f2b(acc[i][j][r] * scale);
            if (w == 0) {
#pragma unroll
                for (int r = 0; r < 4; r++) q[(grow0 + r) * DIM + gcol] = p[r];
            } else {
                const long b = grow0 >> 12;            // batch (SEQ=4096 rows)
                const long t0 = grow0 & (SEQ - 1);
                u16* Ct = (w == 1) ? kt : vt;
                *(u16x4*)(Ct + (b * DIM + gcol) * SEQ + t0) = p;
                if (w == 1) {
#pragma unroll
                    for (int r = 0; r < 4; r++) k[(grow0 + r) * DIM + gcol] = p[r];
                }
            }
        }
    }
}

// ---------------------------------------------------------------------------
// Output GEMM: out[m][n] = sum_k o[m][k] * Wo[n][k], f32 out. 2D grid (32,8).
// ---------------------------------------------------------------------------
__global__ __launch_bounds__(512, 2) void gemm_out(
    const u16* __restrict__ A, const u16* __restrict__ Bw, float* __restrict__ C)
{
    __shared__ __align__(16) u16 L[4 * BUFE];   // 128 KiB
    const Ctx8 c = ctx8(DIM);
    const long row0 = (long)blockIdx.x * GBM;
    const long col0 = (long)blockIdx.y * GBN;

    f32x4 acc[8][4];
#pragma unroll
    for (int i = 0; i < 8; i++)
#pragma unroll
        for (int j = 0; j < 4; j++) {
            f32x4 z = {0.f, 0.f, 0.f, 0.f};
            acc[i][j] = z;
        }

    kloop8(c, A + row0 * DIM, Bw + col0 * DIM, DIM, L, acc);

#pragma unroll
    for (int i = 0; i < 8; i++) {
        const long grow0 = row0 + c.wr * 128 + i * 16 + c.quad * 4;
#pragma unroll
        for (int j = 0; j < 4; j++) {
            const long gcol = col0 + c.wc * 64 + j * 16 + c.m16;
#pragma unroll
            for (int r = 0; r < 4; r++)
                C[(grow0 + r) * DIM + gcol] = acc[i][j][r];
        }
    }
}

// ---------------------------------------------------------------------------
// chunk_kv (MFMA): kvT[blk][e][d] = sum_t Vt[e][t] Kt[d][t]; frags from global.
// ---------------------------------------------------------------------------
__global__ __launch_bounds__(256) void chunk_kv_mfma(
    const u16* __restrict__ Vt, const u16* __restrict__ Kt, u16* __restrict__ KV)
{
    const int tid = threadIdx.x, blk = blockIdx.x;
    const int c = blk & (NC - 1), bh = blk >> 6;
    const int wave = tid >> 6, lane = tid & 63;
    const int wr = wave >> 1, wc = wave & 1;
    const int m16 = lane & 15, quad = lane >> 4;
    const u16* vb = Vt + (long)bh * HD * SEQ + c * CH;
    const u16* kb = Kt + (long)bh * HD * SEQ + c * CH;

    f32x4 acc[4][4];
#pragma unroll
    for (int i = 0; i < 4; i++)
#pragma unroll
        for (int j = 0; j < 4; j++) {
            f32x4 z = {0.f, 0.f, 0.f, 0.f};
            acc[i][j] = z;
        }

#pragma unroll
    for (int tk = 0; tk < 2; tk++) {
        short8 af[4], bf[4];
#pragma unroll
        for (int t = 0; t < 4; t++)
            af[t] = *(const short8*)(vb + (long)(wr * 64 + t * 16 + m16) * SEQ + tk * 32 + quad * 8);
#pragma unroll
        for (int t = 0; t < 4; t++)
            bf[t] = *(const short8*)(kb + (long)(wc * 64 + t * 16 + m16) * SEQ + tk * 32 + quad * 8);
#pragma unroll
        for (int i = 0; i < 4; i++)
#pragma unroll
            for (int j = 0; j < 4; j++)
                acc[i][j] = __builtin_amdgcn_mfma_f32_16x16x32_bf16(
                    af[i], bf[j], acc[i][j], 0, 0, 0);
    }

    u16* outp = KV + (long)blk * (HD * HD);
#pragma unroll
    for (int i = 0; i < 4; i++)
#pragma unroll
        for (int j = 0; j < 4; j++)
#pragma unroll
            for (int r = 0; r < 4; r++)
                outp[(wr * 64 + i * 16 + quad * 4 + r) * HD + wc * 64 + j * 16 + m16]
                    = f2b(acc[i][j][r]);
}

// ---------------------------------------------------------------------------
// exclusive prefix over chunks, in place, u16x4 vectorized.
// grid: 32 bh * 16 sub = 512 blocks, 256 thr; thread owns 4 elems.
// ---------------------------------------------------------------------------
__global__ __launch_bounds__(256) void kv_prefix(u16* __restrict__ KV)
{
    const int bh  = blockIdx.x >> 4;
    const int sub = blockIdx.x & 15;
    const long base = (long)bh * NC * (HD * HD) + (sub * 256 + threadIdx.x) * 4;
    float s0 = 0.f, s1 = 0.f, s2 = 0.f, s3 = 0.f;
#pragma unroll 4
    for (int c = 0; c < NC; c++) {
        u16* p = KV + base + (long)c * (HD * HD);
        u16x4 v = *(u16x4*)p;
        u16x4 w;
        w[0] = f2b(s0); w[1] = f2b(s1); w[2] = f2b(s2); w[3] = f2b(s3);
        *(u16x4*)p = w;
        s0 += b2f(v[0]); s1 += b2f(v[1]); s2 += b2f(v[2]); s3 += b2f(v[3]);
    }
}

// ---------------------------------------------------------------------------
// chunk_out (MFMA): O = mask(Q K^T) V + Q S  per 64-token chunk.
// ---------------------------------------------------------------------------
#define AMP 72   /* padded LDS stride */

__global__ __launch_bounds__(256) void chunk_out_mfma(
    const u16* __restrict__ Q, const u16* __restrict__ Kn,
    const u16* __restrict__ Vt, const u16* __restrict__ Sb, u16* __restrict__ O)
{
    __shared__ __align__(16) u16 Am[CH * AMP];   // 9216 B

    const int tid = threadIdx.x, blk = blockIdx.x;
    const int c = blk & (NC - 1), bh = blk >> 6;
    const int h = bh & (NHEAD - 1), b = bh >> 4;
    const long rowbase = (long)b * SEQ + (long)c * CH;
    const int wave = tid >> 6, lane = tid & 63;   // wave = m-tile
    const int m16 = lane & 15, quad = lane >> 4;

    const u16* qrow = Q  + (rowbase + wave * 16 + m16) * DIM + h * HD;
    const u16* krow = Kn + rowbase * DIM + h * HD;

    short8 qa[4];
#pragma unroll
    for (int dk = 0; dk < 4; dk++)
        qa[dk] = *(const short8*)(qrow + dk * 32 + quad * 8);

    // phase 1: A = mask(Q K^T) -> LDS (A-op layout)
    f32x4 acc1[4];
#pragma unroll
    for (int jt = 0; jt < 4; jt++) {
        f32x4 z = {0.f, 0.f, 0.f, 0.f};
        acc1[jt] = z;
    }
#pragma unroll
    for (int dk = 0; dk < 4; dk++)
#pragma unroll
        for (int jt = 0; jt < 4; jt++) {
            short8 bb = *(const short8*)(krow + (long)(jt * 16 + m16) * DIM + dk * 32 + quad * 8);
            acc1[jt] = __builtin_amdgcn_mfma_f32_16x16x32_bf16(qa[dk], bb, acc1[jt], 0, 0, 0);
        }
    const int mbase = wave * 16 + quad * 4;
#pragma unroll
    for (int jt = 0; jt < 4; jt++) {
        const int j = jt * 16 + m16;
#pragma unroll
        for (int r = 0; r < 4; r++) {
            float v = (j <= mbase + r) ? acc1[jt][r] : 0.f;
            Am[(mbase + r) * AMP + j] = f2b(v);
        }
    }

    // phase 2: acc = Q * S (S^T rows d-contiguous)
    f32x4 acc[8];
#pragma unroll
    for (int et = 0; et < 8; et++) {
        f32x4 z = {0.f, 0.f, 0.f, 0.f};
        acc[et] = z;
    }
    const u16* Sg = Sb + (long)blk * (HD * HD);
#pragma unroll
    for (int dk = 0; dk < 4; dk++)
#pragma unroll
        for (int et = 0; et < 8; et++) {
            short8 sb = *(const short8*)(Sg + (et * 16 + m16) * HD + dk * 32 + quad * 8);
            acc[et] = __builtin_amdgcn_mfma_f32_16x16x32_bf16(qa[dk], sb, acc[et], 0, 0, 0);
        }

    // phase 3: acc += A * V (A from own-wave LDS rows, V^T t-contiguous)
    __syncthreads();
    const u16* vb = Vt + (long)bh * HD * SEQ + c * CH;
#pragma unroll
    for (int tk = 0; tk < 2; tk++) {
        short8 a = *(const short8*)&Am[(wave * 16 + m16) * AMP + tk * 32 + quad * 8];
#pragma unroll
        for (int et = 0; et < 8; et++) {
            short8 vbf = *(const short8*)(vb + (long)(et * 16 + m16) * SEQ + tk * 32 + quad * 8);
            acc[et] = __builtin_amdgcn_mfma_f32_16x16x32_bf16(a, vbf, acc[et], 0, 0, 0);
        }
    }

#pragma unroll
    for (int et = 0; et < 8; et++) {
        const int e = et * 16 + m16;
#pragma unroll
        for (int r = 0; r < 4; r++) {
            const int m = wave * 16 + quad * 4 + r;
            O[(rowbase + m) * DIM + h * HD + e] = f2b(acc[et][r]);
        }
    }
}

// ---------------------------------------------------------------------------
extern "C" void kernel_launch(void* const* d_in, const int* in_sizes, int n_in,
                              void* d_out, int out_size, void* d_ws, size_t ws_size,
                              hipStream_t stream)
{
    (void)in_sizes; (void)n_in; (void)out_size; (void)ws_size;
    const float* x  = (const float*)d_in[0];
    const float* Wq = (const float*)d_in[1];
    const float* Wk = (const float*)d_in[2];
    const float* Wv = (const float*)d_in[3];
    const float* Wo = (const float*)d_in[4];
    float* out = (float*)d_out;

    const long NE = (long)MROWS * DIM;        // 16,777,216 elements
    const long WE = (long)DIM * DIM;          //  4,194,304 elements
    u16* xb  = (u16*)d_ws;                    // 33.5 MB
    u16* Wqb = xb  + NE;
    u16* Wkb = Wqb + WE;
    u16* Wvb = Wkb + WE;
    u16* Wob = Wvb + WE;
    u16* q   = Wob + WE;                      // 33.5 MB each
    u16* k   = q + NE;
    u16* vt  = k + NE;                        // transposed [b,h,e][t]
    u16* kv  = vt + NE;                       // 67.1 MB (prefix state per chunk)
    u16* o   = xb;                            // alias: xb dead after projections
    u16* kt  = (u16*)d_out;                   // scratch in d_out (overwritten later)

    hipLaunchKernelGGL(cast_all, dim3(16384), dim3(256), 0, stream,
                       x, Wq, Wk, Wv, Wo, xb, Wqb, Wkb, Wvb, Wob);

    const float qscale = 0.08838834764831845f;  // HD^-0.5

    hipLaunchKernelGGL(gemm_qkv, dim3(MROWS / GBM, 24), dim3(512), 0, stream,
                       xb, Wqb, Wkb, Wvb, q, k, kt, vt, qscale);

    hipLaunchKernelGGL(chunk_kv_mfma, dim3(NBATCH * NHEAD * NC), dim3(256), 0, stream, vt, kt, kv);
    hipLaunchKernelGGL(kv_prefix,     dim3(512),                 dim3(256), 0, stream, kv);
    hipLaunchKernelGGL(chunk_out_mfma,dim3(NBATCH * NHEAD * NC), dim3(256), 0, stream, q, k, vt, kv, o);

    hipLaunchKernelGGL(gemm_out, dim3(MROWS / GBM, DIM / GBN), dim3(512), 0, stream, o, Wob, out);
}